// Round 8
// baseline (210.565 us; speedup 1.0000x reference)
//
#include <hip/hip_runtime.h>
#include <stdint.h>

#define NN   4096
#define KK   32
#define HID  128
#define BLK  256
#define CAP  128

typedef unsigned short bf16_t;
typedef __attribute__((ext_vector_type(8))) short bf16x8;
typedef __attribute__((ext_vector_type(4))) float f32x4;

__device__ __forceinline__ bf16_t f2bf(float f) {
    uint32_t u = __float_as_uint(f);
    u = u + 0x7fffu + ((u >> 16) & 1u);   // round-to-nearest-even
    return (bf16_t)(u >> 16);
}
__device__ __forceinline__ float siluf(float x) {
    return x / (1.0f + __expf(-x));
}

// ---- prepack: W2 fp32 -> bf16, laid out in MFMA B-fragment order ----
__global__ __launch_bounds__(BLK) void prepack_w2(
    const float* __restrict__ W2, uint4* __restrict__ w2b)
{
    int c  = blockIdx.x * BLK + threadIdx.x;
    int f  = c >> 6, ln = c & 63;
    int nh = f >> 4, nt = (f >> 2) & 3, kk = f & 3;
    int row = nh*64 + nt*16 + (ln & 15);
    int k0  = kk*32 + (ln >> 4) * 8;
    const float* s = W2 + row * HID + k0;
    float4 lo = *(const float4*)s;
    float4 hi = *(const float4*)(s + 4);
    uint4 pk;
    pk.x = (uint32_t)f2bf(lo.x) | ((uint32_t)f2bf(lo.y) << 16);
    pk.y = (uint32_t)f2bf(lo.z) | ((uint32_t)f2bf(lo.w) << 16);
    pk.z = (uint32_t)f2bf(hi.x) | ((uint32_t)f2bf(hi.y) << 16);
    pk.w = (uint32_t)f2bf(hi.z) | ((uint32_t)f2bf(hi.w) << 16);
    w2b[c] = pk;
}

template<bool WS>
struct __align__(16) Sm {
    union __align__(16) {                 // phase-disjoint reuse
        uint32_t hist[1024];              // 4 KB  (dist + pivot scan)
        ushort h1[KK * HID];              // 8 KB  (MLP A-operand, swizzled)
    } u;
    uint32_t w2l[WS ? 4 : HID * 64];      // W2 staged only in no-workspace fallback
    unsigned long long cand[CAP];         // 1 KB, NOT aliased with hist
    float ssq[2][KK];
    float sedge[2][KK];
    int recvs[KK];
    unsigned long long redk[4];
    int pivotB;
    int cnt;
    int chosen;
};

template<bool WS>
__global__ __launch_bounds__(BLK) void egnn_main(
    const float* __restrict__ pos, const float* __restrict__ tptr,
    const float* __restrict__ W1,  const float* __restrict__ b1,
    const float* __restrict__ g1,  const float* __restrict__ W2,
    const float* __restrict__ b2,  const float* __restrict__ g2,
    const float* __restrict__ W3,  const float* __restrict__ b3,
    const uint4* __restrict__ w2b, float* __restrict__ out)
{
    __shared__ Sm<WS> sm;
    const int tid  = threadIdx.x;
    const int lane = tid & 63;
    const int wid  = tid >> 6;
    const int i    = blockIdx.x;
    const int l15  = lane & 15, lq = lane >> 4;
    const int mh   = wid & 1,   nh = wid >> 1;   // MFMA tile role

    // ---- layer-1 per-lane constants: neurons 2*lane, 2*lane+1 ----
    const float ts   = tptr[0];
    const float4 w1v = ((const float4*)W1)[lane];     // (a0,b0,a1,b1)
    const float2 b1v = ((const float2*)b1)[lane];
    const float2 g1v = ((const float2*)g1)[lane];
    const float tc0  = ts * w1v.y + b1v.x;
    const float tc1  = ts * w1v.w + b1v.y;
    const float b3s  = b3[0];
    // closed-form RMS coefficients: sq(rad) = rad^2*A2 + 2*rad*AC + C2
    float A2 = w1v.x*w1v.x + w1v.z*w1v.z;
    float AC = w1v.x*tc0   + w1v.z*tc1;
    float C2 = tc0*tc0     + tc1*tc1;
    #pragma unroll
    for (int m = 32; m >= 1; m >>= 1) {
        A2 += __shfl_xor(A2, m, 64);
        AC += __shfl_xor(AC, m, 64);
        C2 += __shfl_xor(C2, m, 64);
    }
    // ---- epilogue per-lane constants (MFMA D-layout: n = nh*64 + nt*16 + l15) ----
    float g2v[4], w3v[4], b2v[4];
    #pragma unroll
    for (int nt = 0; nt < 4; ++nt) {
        int n = nh*64 + nt*16 + l15;
        g2v[nt] = g2[n]; w3v[nt] = W3[n]; b2v[nt] = b2[n];
    }

    if constexpr (!WS) {
        for (int idx = tid; idx < HID * 16; idx += BLK) {
            int row = idx >> 4, c = idx & 15;
            const float* src = W2 + row * HID + c * 8;
            float4 lo = *(const float4*)src;
            float4 hi = *(const float4*)(src + 4);
            uint4 pk;
            pk.x = (uint32_t)f2bf(lo.x) | ((uint32_t)f2bf(lo.y) << 16);
            pk.y = (uint32_t)f2bf(lo.z) | ((uint32_t)f2bf(lo.w) << 16);
            pk.z = (uint32_t)f2bf(hi.x) | ((uint32_t)f2bf(hi.y) << 16);
            pk.w = (uint32_t)f2bf(hi.z) | ((uint32_t)f2bf(hi.w) << 16);
            *((uint4*)&sm.w2l[row * 64 + 4 * (c ^ (row & 15))]) = pk;
        }
    }
    ((uint4*)sm.u.hist)[tid] = uint4{0u, 0u, 0u, 0u};
    if (tid == 0) sm.cnt = 0;
    __syncthreads();                                           // B1

    const float px = pos[3*i], py = pos[3*i+1], pz = pos[3*i+2];

    // ---- distances into registers (exact fp32 chain) + LDS histogram ----
    float dreg[4][4];
    {
        const float4* p4 = (const float4*)pos;
        #pragma unroll
        for (int g = 0; g < 4; ++g) {
            float4 f0 = p4[768*g + 3*tid];
            float4 f1 = p4[768*g + 3*tid + 1];
            float4 f2 = p4[768*g + 3*tid + 2];
            float jx[4] = {f0.x, f0.w, f1.z, f2.y};
            float jy[4] = {f0.y, f1.x, f1.w, f2.z};
            float jz[4] = {f0.z, f1.y, f2.x, f2.w};
            #pragma unroll
            for (int c = 0; c < 4; ++c) {
                float dx = px - jx[c];
                float dy = py - jy[c];
                float dz = pz - jz[c];
                float d = __fadd_rn(__fadd_rn(__fmul_rn(dx,dx), __fmul_rn(dy,dy)),
                                    __fmul_rn(dz,dz));
                dreg[g][c] = d;
                atomicAdd((int*)&sm.u.hist[__float_as_uint(d) >> 21], 1);
            }
        }
    }
    if (((i & 1023) >> 2) == tid) dreg[i >> 10][i & 3] = __uint_as_float(0x7f800000u);
    if (tid == 0) atomicAdd((int*)&sm.u.hist[0], -1);   // remove self's bucket-0 entry
    __syncthreads();                                           // B2

    // ---- pivot bucket: each wave scans the WHOLE hist independently (no x-wave sync)
    {
        const uint4 q0 = ((const uint4*)sm.u.hist)[lane*4    ];
        const uint4 q1 = ((const uint4*)sm.u.hist)[lane*4 + 1];
        const uint4 q2 = ((const uint4*)sm.u.hist)[lane*4 + 2];
        const uint4 q3 = ((const uint4*)sm.u.hist)[lane*4 + 3];
        int h[16] = {(int)q0.x,(int)q0.y,(int)q0.z,(int)q0.w,
                     (int)q1.x,(int)q1.y,(int)q1.z,(int)q1.w,
                     (int)q2.x,(int)q2.y,(int)q2.z,(int)q2.w,
                     (int)q3.x,(int)q3.y,(int)q3.z,(int)q3.w};
        int s = 0;
        #pragma unroll
        for (int t = 0; t < 16; ++t) s += h[t];
        int incl = s;
        #pragma unroll
        for (int off = 1; off < 64; off <<= 1) {
            int v = __shfl_up(incl, off, 64);
            if (lane >= off) incl += v;
        }
        int E = incl - s;
        if (E < KK && E + s >= KK) {
            int cum = E, B = lane*16 + 15;
            bool found = false;
            #pragma unroll
            for (int t = 0; t < 16; ++t) {
                if (!found && cum + h[t] >= KK) { B = lane*16 + t; found = true; }
                cum += h[t];
            }
            sm.pivotB = B;          // all waves compute the same value
        }
    }
    // wave-local visibility of pivotB is ordered by lgkmcnt (same-wave write/read)

    // ---- compaction from registers into cand (separate buffer; no alias race) ----
    {
        const int B = sm.pivotB;
        #pragma unroll
        for (int g = 0; g < 4; ++g) {
            #pragma unroll
            for (int c = 0; c < 4; ++c) {
                uint32_t ub = __float_as_uint(dreg[g][c]);   // self=inf -> bucket > B
                if ((int)(ub >> 21) <= B) {
                    int slot = atomicAdd(&sm.cnt, 1);
                    if (slot < CAP)
                        sm.cand[slot] = (((unsigned long long)ub) << 12)
                                      | (unsigned)(1024*g + 4*tid + c);
                }
            }
        }
    }
    __syncthreads();                                           // B3

    const int cnt = sm.cnt;
    if (cnt <= CAP) {
        if (tid < cnt) {
            unsigned long long km = sm.cand[tid];
            int rank = 0;
            for (int q = 0; q < cnt; ++q)
                rank += (sm.cand[q] < km) ? 1 : 0;
            if (rank < KK) sm.recvs[rank] = (int)(km & 0xFFFull);
        }
    } else {
        // fallback (tie overflow; essentially never): exact 32-pass argmin over regs
        for (int it = 0; it < KK; ++it) {
            unsigned long long best = ~0ull;
            #pragma unroll
            for (int g = 0; g < 4; ++g)
                #pragma unroll
                for (int c = 0; c < 4; ++c) {
                    unsigned long long key =
                        (((unsigned long long)__float_as_uint(dreg[g][c])) << 12)
                        | (unsigned)(1024*g + 4*tid + c);
                    best = best < key ? best : key;
                }
            #pragma unroll
            for (int m = 32; m >= 1; m >>= 1) {
                unsigned long long o = __shfl_xor(best, m, 64);
                best = best < o ? best : o;
            }
            if (lane == 0) sm.redk[wid] = best;
            __syncthreads();
            if (tid == 0) {
                unsigned long long b01 = sm.redk[0] < sm.redk[1] ? sm.redk[0] : sm.redk[1];
                unsigned long long b23 = sm.redk[2] < sm.redk[3] ? sm.redk[2] : sm.redk[3];
                unsigned long long b   = b01 < b23 ? b01 : b23;
                int j = (int)(b & 0xfffull);
                sm.recvs[it] = j;
                sm.chosen = j;
            }
            __syncthreads();
            int j = sm.chosen;
            if (((j & 1023) >> 2) == tid)
                dreg[j >> 10][j & 3] = __uint_as_float(0x7f800000u);
        }
    }
    __syncthreads();                                           // B4

    // ---- lane-parallel edge gather (all waves redundantly; lanes 0..31) ----
    float radL = 0.f, cdxL = 0.f, cdyL = 0.f, cdzL = 0.f;
    if (lane < KK) {
        int r = sm.recvs[lane];
        cdxL = px - pos[3*r];
        cdyL = py - pos[3*r+1];
        cdzL = pz - pos[3*r+2];
        radL = __fadd_rn(__fadd_rn(__fmul_rn(cdxL,cdxL), __fmul_rn(cdyL,cdyL)),
                         __fmul_rn(cdzL,cdzL));
    }

    // ---- layer 1: wave owns edges [8*wid, 8*wid+8); closed-form RMS ----
    const int eb = wid * 8;
    {
        uint32_t* h1d = (uint32_t*)sm.u.h1;
        const int ch = lane >> 2, dw = lane & 3;
        #pragma unroll
        for (int e = 0; e < 8; ++e) {
            float rad = __shfl(radL, eb + e, 64);
            float sqv = rad*rad*A2 + 2.0f*rad*AC + C2;
            float rn  = rsqrtf(sqv * (1.0f/HID) + 1e-5f);
            float p0  = rad * w1v.x + tc0;
            float p1  = rad * w1v.z + tc1;
            float a = siluf(p0 * rn * g1v.x);
            float b = siluf(p1 * rn * g1v.y);
            uint32_t pk = (__float_as_uint(a) >> 16) | (__float_as_uint(b) & 0xffff0000u);
            int ge = eb + e;
            h1d[ge*64 + ((ch ^ (ge & 15)))*4 + dw] = pk;
        }
    }
    __syncthreads();                                           // B5

    // ---- layer 2 via MFMA (bias folded into acc init) ----
    f32x4 acc0 = {b2v[0],b2v[0],b2v[0],b2v[0]};
    f32x4 acc1 = {b2v[1],b2v[1],b2v[1],b2v[1]};
    f32x4 acc2 = {b2v[2],b2v[2],b2v[2],b2v[2]};
    f32x4 acc3 = {b2v[3],b2v[3],b2v[3],b2v[3]};
    {
        const bf16x8* h1v = (const bf16x8*)sm.u.h1;   // [32][16 chunks]
        const int m = mh*16 + l15;
        if constexpr (WS) {
            const bf16x8* bv = (const bf16x8*)w2b;
            #pragma unroll
            for (int kk = 0; kk < 4; ++kk) {
                bf16x8 af = h1v[m*16 + ((kk*4 + lq) ^ l15)];
                acc0 = __builtin_amdgcn_mfma_f32_16x16x32_bf16(
                           af, bv[((nh*4+0)*4 + kk)*64 + lane], acc0, 0, 0, 0);
                acc1 = __builtin_amdgcn_mfma_f32_16x16x32_bf16(
                           af, bv[((nh*4+1)*4 + kk)*64 + lane], acc1, 0, 0, 0);
                acc2 = __builtin_amdgcn_mfma_f32_16x16x32_bf16(
                           af, bv[((nh*4+2)*4 + kk)*64 + lane], acc2, 0, 0, 0);
                acc3 = __builtin_amdgcn_mfma_f32_16x16x32_bf16(
                           af, bv[((nh*4+3)*4 + kk)*64 + lane], acc3, 0, 0, 0);
            }
        } else {
            const bf16x8* w2v = (const bf16x8*)sm.w2l;    // [128][16 chunks]
            const int nrow0 = (nh*64 +      l15) * 16;
            const int nrow1 = (nh*64 + 16 + l15) * 16;
            const int nrow2 = (nh*64 + 32 + l15) * 16;
            const int nrow3 = (nh*64 + 48 + l15) * 16;
            #pragma unroll
            for (int kk = 0; kk < 4; ++kk) {
                const int q = (kk*4 + lq) ^ l15;
                bf16x8 af = h1v[m*16 + q];
                acc0 = __builtin_amdgcn_mfma_f32_16x16x32_bf16(af, w2v[nrow0 + q], acc0, 0, 0, 0);
                acc1 = __builtin_amdgcn_mfma_f32_16x16x32_bf16(af, w2v[nrow1 + q], acc1, 0, 0, 0);
                acc2 = __builtin_amdgcn_mfma_f32_16x16x32_bf16(af, w2v[nrow2 + q], acc2, 0, 0, 0);
                acc3 = __builtin_amdgcn_mfma_f32_16x16x32_bf16(af, w2v[nrow3 + q], acc3, 0, 0, 0);
            }
        }
    }

    // ---- epilogue: RMSNorm over 128 (cross-half via LDS), silu, dot W3 ----
    float ss[4];
    #pragma unroll
    for (int r = 0; r < 4; ++r)
        ss[r] = acc0[r]*acc0[r] + acc1[r]*acc1[r] + acc2[r]*acc2[r] + acc3[r]*acc3[r];
    #pragma unroll
    for (int m = 8; m >= 1; m >>= 1) {
        #pragma unroll
        for (int r = 0; r < 4; ++r) ss[r] += __shfl_xor(ss[r], m, 64);
    }
    if (l15 == 0) {
        #pragma unroll
        for (int r = 0; r < 4; ++r) sm.ssq[nh][mh*16 + lq*4 + r] = ss[r];
    }
    __syncthreads();                                           // B6

    float sp[4];
    #pragma unroll
    for (int r = 0; r < 4; ++r) {
        int e = mh*16 + lq*4 + r;
        float rn = rsqrtf((sm.ssq[0][e] + sm.ssq[1][e]) * (1.0f/HID) + 1e-5f);
        sp[r] = siluf(acc0[r] * rn * g2v[0]) * w3v[0]
              + siluf(acc1[r] * rn * g2v[1]) * w3v[1]
              + siluf(acc2[r] * rn * g2v[2]) * w3v[2]
              + siluf(acc3[r] * rn * g2v[3]) * w3v[3];
    }
    #pragma unroll
    for (int m = 8; m >= 1; m >>= 1) {
        #pragma unroll
        for (int r = 0; r < 4; ++r) sp[r] += __shfl_xor(sp[r], m, 64);
    }
    if (l15 == 0) {
        #pragma unroll
        for (int r = 0; r < 4; ++r) sm.sedge[nh][mh*16 + lq*4 + r] = sp[r];
    }
    __syncthreads();                                           // B7

    // ---- final: wave 0 lane-parallel message sum (lanes hold cd for edge=lane) ----
    if (wid == 0) {
        float s  = (lane < KK) ? (sm.sedge[0][lane] + sm.sedge[1][lane] + b3s) : 0.f;
        float mx = cdxL * s, my = cdyL * s, mz = cdzL * s;
        #pragma unroll
        for (int m = 16; m >= 1; m >>= 1) {
            mx += __shfl_xor(mx, m, 64);
            my += __shfl_xor(my, m, 64);
            mz += __shfl_xor(mz, m, 64);
        }
        if (lane == 0) {
            out[3*i    ] = px + mx * (1.0f/KK);
            out[3*i + 1] = py + my * (1.0f/KK);
            out[3*i + 2] = pz + mz * (1.0f/KK);
        }
    }
}

extern "C" void kernel_launch(void* const* d_in, const int* in_sizes, int n_in,
                              void* d_out, int out_size, void* d_ws, size_t ws_size,
                              hipStream_t stream) {
    (void)in_sizes; (void)n_in; (void)out_size;
    const float* pos = (const float*)d_in[0];
    const float* t   = (const float*)d_in[1];
    const float* W1  = (const float*)d_in[2];
    const float* b1  = (const float*)d_in[3];
    const float* g1  = (const float*)d_in[4];
    const float* W2  = (const float*)d_in[5];
    const float* b2  = (const float*)d_in[6];
    const float* g2  = (const float*)d_in[7];
    const float* W3  = (const float*)d_in[8];
    const float* b3  = (const float*)d_in[9];
    float* out = (float*)d_out;

    if (d_ws != nullptr && ws_size >= 32768) {
        prepack_w2<<<8, BLK, 0, stream>>>(W2, (uint4*)d_ws);
        egnn_main<true><<<NN, BLK, 0, stream>>>(
            pos, t, W1, b1, g1, W2, b2, g2, W3, b3, (const uint4*)d_ws, out);
    } else {
        egnn_main<false><<<NN, BLK, 0, stream>>>(
            pos, t, W1, b1, g1, W2, b2, g2, W3, b3, nullptr, out);
    }
}

// Round 9
// 136.732 us; speedup vs baseline: 1.5400x; 1.5400x over previous
//
#include <hip/hip_runtime.h>
#include <stdint.h>

#define NN   4096
#define KK   32
#define HID  128
#define BLK  256
#define CAP  256

typedef unsigned short bf16_t;
typedef __attribute__((ext_vector_type(8))) short bf16x8;
typedef __attribute__((ext_vector_type(4))) float f32x4;

__device__ __forceinline__ bf16_t f2bf(float f) {
    uint32_t u = __float_as_uint(f);
    u = u + 0x7fffu + ((u >> 16) & 1u);   // round-to-nearest-even
    return (bf16_t)(u >> 16);
}
__device__ __forceinline__ float siluf(float x) {
    return x / (1.0f + __expf(-x));
}

// ---- prepack: W2 fp32 -> bf16, laid out in MFMA B-fragment order ----
__global__ __launch_bounds__(BLK) void prepack_w2(
    const float* __restrict__ W2, uint4* __restrict__ w2b)
{
    int c  = blockIdx.x * BLK + threadIdx.x;
    int f  = c >> 6, ln = c & 63;
    int nh = f >> 4, nt = (f >> 2) & 3, kk = f & 3;
    int row = nh*64 + nt*16 + (ln & 15);
    int k0  = kk*32 + (ln >> 4) * 8;
    const float* s = W2 + row * HID + k0;
    float4 lo = *(const float4*)s;
    float4 hi = *(const float4*)(s + 4);
    uint4 pk;
    pk.x = (uint32_t)f2bf(lo.x) | ((uint32_t)f2bf(lo.y) << 16);
    pk.y = (uint32_t)f2bf(lo.z) | ((uint32_t)f2bf(lo.w) << 16);
    pk.z = (uint32_t)f2bf(hi.x) | ((uint32_t)f2bf(hi.y) << 16);
    pk.w = (uint32_t)f2bf(hi.z) | ((uint32_t)f2bf(hi.w) << 16);
    w2b[c] = pk;
}

template<bool WS>
struct __align__(16) Sm {
    union __align__(16) {                 // phase-disjoint reuse
        uint32_t hist[1024];              // 4 KB  (dist phase)
        unsigned long long cand[CAP];     // 2 KB  (selection)
        ushort h1[KK * HID];              // 8 KB  (MLP: bf16, 16B chunks ^(edge&15))
    } u;
    uint32_t w2l[WS ? 4 : HID * 64];      // only the no-workspace fallback stages W2
    float ssq[2][KK];
    float sedge[2][KK];
    int recvs[KK];
    float wtr[4][3];
    int waveTot[4];
    unsigned long long redk[4];
    int pivotB;
    int cnt;
    int chosen;
};

template<bool WS>
__global__ __launch_bounds__(BLK) void egnn_main(
    const float* __restrict__ pos, const float* __restrict__ tptr,
    const float* __restrict__ W1,  const float* __restrict__ b1,
    const float* __restrict__ g1,  const float* __restrict__ W2,
    const float* __restrict__ b2,  const float* __restrict__ g2,
    const float* __restrict__ W3,  const float* __restrict__ b3,
    const uint4* __restrict__ w2b, float* __restrict__ out)
{
    __shared__ Sm<WS> sm;
    const int tid  = threadIdx.x;
    const int lane = tid & 63;
    const int wid  = tid >> 6;
    const int i    = blockIdx.x;
    const int l15  = lane & 15, lq = lane >> 4;
    const int mh   = wid & 1,   nh = wid >> 1;   // MFMA tile role

    // ---- layer-1 per-lane constants: neurons 2*lane, 2*lane+1 (adjacent pair) ----
    const float ts   = tptr[0];
    const float4 w1v = ((const float4*)W1)[lane];     // rows 2l,2l+1: (a0,b0,a1,b1)
    const float2 b1v = ((const float2*)b1)[lane];
    const float2 g1v = ((const float2*)g1)[lane];
    const float tc0  = ts * w1v.y + b1v.x;
    const float tc1  = ts * w1v.w + b1v.y;
    const float b3s  = b3[0];
    // closed-form RMS coefficients: sum_n (rad*a_n + c_n)^2 = rad^2*A2 + 2*rad*AC + C2
    float A2 = w1v.x*w1v.x + w1v.z*w1v.z;
    float AC = w1v.x*tc0   + w1v.z*tc1;
    float C2 = tc0*tc0     + tc1*tc1;
    #pragma unroll
    for (int m = 32; m >= 1; m >>= 1) {
        A2 += __shfl_xor(A2, m, 64);
        AC += __shfl_xor(AC, m, 64);
        C2 += __shfl_xor(C2, m, 64);
    }
    // ---- epilogue per-lane constants (MFMA D-layout: n = nh*64 + nt*16 + l15) ----
    float g2v[4], w3v[4], b2v[4];
    #pragma unroll
    for (int nt = 0; nt < 4; ++nt) {
        int n = nh*64 + nt*16 + l15;
        g2v[nt] = g2[n]; w3v[nt] = W3[n]; b2v[nt] = b2[n];
    }

    if constexpr (!WS) {
        // fallback: stage W2 into LDS (bf16, 16B chunks XOR-swizzled by row&15)
        for (int idx = tid; idx < HID * 16; idx += BLK) {
            int row = idx >> 4, c = idx & 15;
            const float* src = W2 + row * HID + c * 8;
            float4 lo = *(const float4*)src;
            float4 hi = *(const float4*)(src + 4);
            uint4 pk;
            pk.x = (uint32_t)f2bf(lo.x) | ((uint32_t)f2bf(lo.y) << 16);
            pk.y = (uint32_t)f2bf(lo.z) | ((uint32_t)f2bf(lo.w) << 16);
            pk.z = (uint32_t)f2bf(hi.x) | ((uint32_t)f2bf(hi.y) << 16);
            pk.w = (uint32_t)f2bf(hi.z) | ((uint32_t)f2bf(hi.w) << 16);
            *((uint4*)&sm.w2l[row * 64 + 4 * (c ^ (row & 15))]) = pk;
        }
    }
    ((uint4*)sm.u.hist)[tid] = uint4{0u, 0u, 0u, 0u};   // 1024 dwords, one uint4/thread
    if (tid == 0) sm.cnt = 0;
    __syncthreads();

    const float px = pos[3*i], py = pos[3*i+1], pz = pos[3*i+2];

    // ---- distances into REGISTERS (exact fp32 chain) + LDS histogram ----
    // thread covers j = 1024*g + 4*tid + c  (g<4, c<4); pos read as 3x float4.
    // self-distance computes to exactly 0.0 (bucket 0) and is patched afterwards.
    float dreg[4][4];
    {
        const float4* p4 = (const float4*)pos;
        #pragma unroll
        for (int g = 0; g < 4; ++g) {
            float4 f0 = p4[768*g + 3*tid];
            float4 f1 = p4[768*g + 3*tid + 1];
            float4 f2 = p4[768*g + 3*tid + 2];
            float jx[4] = {f0.x, f0.w, f1.z, f2.y};
            float jy[4] = {f0.y, f1.x, f1.w, f2.z};
            float jz[4] = {f0.z, f1.y, f2.x, f2.w};
            #pragma unroll
            for (int c = 0; c < 4; ++c) {
                float dx = px - jx[c];
                float dy = py - jy[c];
                float dz = pz - jz[c];
                float d = __fadd_rn(__fadd_rn(__fmul_rn(dx,dx), __fmul_rn(dy,dy)),
                                    __fmul_rn(dz,dz));
                dreg[g][c] = d;
                atomicAdd((int*)&sm.u.hist[__float_as_uint(d) >> 21], 1);
            }
        }
    }
    if (((i & 1023) >> 2) == tid) dreg[i >> 10][i & 3] = __uint_as_float(0x7f800000u);
    if (tid == 0) atomicAdd((int*)&sm.u.hist[0], -1);   // remove self's bucket-0 entry
    __syncthreads();

    // ---- pivot bucket B: first bucket where cumulative count >= KK ----
    {
        const int b0 = tid * 4;
        int h0 = (int)sm.u.hist[b0],   hA = (int)sm.u.hist[b0+1];
        int h2 = (int)sm.u.hist[b0+2], h3 = (int)sm.u.hist[b0+3];
        int s = h0 + hA + h2 + h3;
        int incl = s;
        #pragma unroll
        for (int off = 1; off < 64; off <<= 1) {
            int v = __shfl_up(incl, off, 64);
            if (lane >= off) incl += v;
        }
        if (lane == 63) sm.waveTot[wid] = incl;
        __syncthreads();
        int base = 0;
        for (int w = 0; w < wid; ++w) base += sm.waveTot[w];
        int E = base + incl - s;
        if (E < KK && E + s >= KK) {
            int cum = E, B = b0 + 3;
            if (cum + h0 >= KK) B = b0;
            else { cum += h0;
                if (cum + hA >= KK) B = b0 + 1;
                else { cum += hA;
                    if (cum + h2 >= KK) B = b0 + 2;
                }
            }
            sm.pivotB = B;
        }
    }
    __syncthreads();

    // ---- compaction from registers: keys with bucket <= B (cand aliases hist) ----
    {
        const int B = sm.pivotB;
        #pragma unroll
        for (int g = 0; g < 4; ++g) {
            #pragma unroll
            for (int c = 0; c < 4; ++c) {
                uint32_t ub = __float_as_uint(dreg[g][c]);   // self=inf -> bucket 1020 > B
                if ((int)(ub >> 21) <= B) {
                    int slot = atomicAdd(&sm.cnt, 1);
                    if (slot < CAP)
                        sm.u.cand[slot] = (((unsigned long long)ub) << 12)
                                        | (unsigned)(1024*g + 4*tid + c);
                }
            }
        }
    }
    __syncthreads();

    const int cnt = sm.cnt;
    if (cnt <= CAP) {
        if (tid < cnt) {
            unsigned long long km = sm.u.cand[tid];
            int rank = 0;
            for (int q = 0; q < cnt; ++q)
                rank += (sm.u.cand[q] < km) ? 1 : 0;
            if (rank < KK) sm.recvs[rank] = (int)(km & 0xFFFull);
        }
    } else {
        // fallback (tie overflow; essentially never): exact 32-pass argmin over regs
        for (int it = 0; it < KK; ++it) {
            unsigned long long best = ~0ull;
            #pragma unroll
            for (int g = 0; g < 4; ++g)
                #pragma unroll
                for (int c = 0; c < 4; ++c) {
                    unsigned long long key =
                        (((unsigned long long)__float_as_uint(dreg[g][c])) << 12)
                        | (unsigned)(1024*g + 4*tid + c);
                    best = best < key ? best : key;
                }
            #pragma unroll
            for (int m = 32; m >= 1; m >>= 1) {
                unsigned long long o = __shfl_xor(best, m, 64);
                best = best < o ? best : o;
            }
            if (lane == 0) sm.redk[wid] = best;
            __syncthreads();
            if (tid == 0) {
                unsigned long long b01 = sm.redk[0] < sm.redk[1] ? sm.redk[0] : sm.redk[1];
                unsigned long long b23 = sm.redk[2] < sm.redk[3] ? sm.redk[2] : sm.redk[3];
                unsigned long long b   = b01 < b23 ? b01 : b23;
                int j = (int)(b & 0xfffull);
                sm.recvs[it] = j;
                sm.chosen = j;
            }
            __syncthreads();
            int j = sm.chosen;
            if (((j & 1023) >> 2) == tid)
                dreg[j >> 10][j & 3] = __uint_as_float(0x7f800000u);
        }
    }
    __syncthreads();   // recvs visible; hist/cand dead (h1 will overwrite union)

    // ---- geometry + layer 1: wave owns edges [8*wid, 8*wid+8); closed-form RMS ----
    const int eb = wid * 8;
    float cdx[8], cdy[8], cdz[8];
    {
        uint32_t* h1d = (uint32_t*)sm.u.h1;
        const int ch = lane >> 2, dw = lane & 3;
        #pragma unroll
        for (int e = 0; e < 8; ++e) {
            int r = sm.recvs[eb + e];
            float dx = px - pos[3*r];
            float dy = py - pos[3*r+1];
            float dz = pz - pos[3*r+2];
            cdx[e] = dx; cdy[e] = dy; cdz[e] = dz;
            float rad = __fadd_rn(__fadd_rn(__fmul_rn(dx,dx), __fmul_rn(dy,dy)),
                                  __fmul_rn(dz,dz));
            float sqv = rad*rad*A2 + 2.0f*rad*AC + C2;
            float rn  = rsqrtf(sqv * (1.0f/HID) + 1e-5f);
            float p0  = rad * w1v.x + tc0;
            float p1  = rad * w1v.z + tc1;
            float a = siluf(p0 * rn * g1v.x);
            float b = siluf(p1 * rn * g1v.y);
            uint32_t pk = (__float_as_uint(a) >> 16) | (__float_as_uint(b) & 0xffff0000u);
            int ge = eb + e;
            h1d[ge*64 + ((ch ^ (ge & 15)))*4 + dw] = pk;
        }
    }
    __syncthreads();

    // ---- layer 2 via MFMA (b2 folded into accumulator init) ----
    f32x4 acc0 = {b2v[0],b2v[0],b2v[0],b2v[0]};
    f32x4 acc1 = {b2v[1],b2v[1],b2v[1],b2v[1]};
    f32x4 acc2 = {b2v[2],b2v[2],b2v[2],b2v[2]};
    f32x4 acc3 = {b2v[3],b2v[3],b2v[3],b2v[3]};
    {
        const bf16x8* h1v = (const bf16x8*)sm.u.h1;   // [32][16 chunks]
        const int m = mh*16 + l15;
        if constexpr (WS) {
            const bf16x8* bv = (const bf16x8*)w2b;
            #pragma unroll
            for (int kk = 0; kk < 4; ++kk) {
                bf16x8 af = h1v[m*16 + ((kk*4 + lq) ^ l15)];
                acc0 = __builtin_amdgcn_mfma_f32_16x16x32_bf16(
                           af, bv[((nh*4+0)*4 + kk)*64 + lane], acc0, 0, 0, 0);
                acc1 = __builtin_amdgcn_mfma_f32_16x16x32_bf16(
                           af, bv[((nh*4+1)*4 + kk)*64 + lane], acc1, 0, 0, 0);
                acc2 = __builtin_amdgcn_mfma_f32_16x16x32_bf16(
                           af, bv[((nh*4+2)*4 + kk)*64 + lane], acc2, 0, 0, 0);
                acc3 = __builtin_amdgcn_mfma_f32_16x16x32_bf16(
                           af, bv[((nh*4+3)*4 + kk)*64 + lane], acc3, 0, 0, 0);
            }
        } else {
            const bf16x8* w2v = (const bf16x8*)sm.w2l;    // [128][16 chunks]
            const int nrow0 = (nh*64 +      l15) * 16;
            const int nrow1 = (nh*64 + 16 + l15) * 16;
            const int nrow2 = (nh*64 + 32 + l15) * 16;
            const int nrow3 = (nh*64 + 48 + l15) * 16;
            #pragma unroll
            for (int kk = 0; kk < 4; ++kk) {
                const int q = (kk*4 + lq) ^ l15;
                bf16x8 af = h1v[m*16 + q];
                acc0 = __builtin_amdgcn_mfma_f32_16x16x32_bf16(af, w2v[nrow0 + q], acc0, 0, 0, 0);
                acc1 = __builtin_amdgcn_mfma_f32_16x16x32_bf16(af, w2v[nrow1 + q], acc1, 0, 0, 0);
                acc2 = __builtin_amdgcn_mfma_f32_16x16x32_bf16(af, w2v[nrow2 + q], acc2, 0, 0, 0);
                acc3 = __builtin_amdgcn_mfma_f32_16x16x32_bf16(af, w2v[nrow3 + q], acc3, 0, 0, 0);
            }
        }
    }

    // ---- epilogue: RMSNorm over 128 (cross-half via LDS), silu, dot W3 ----
    float ss[4];
    #pragma unroll
    for (int r = 0; r < 4; ++r)
        ss[r] = acc0[r]*acc0[r] + acc1[r]*acc1[r] + acc2[r]*acc2[r] + acc3[r]*acc3[r];
    #pragma unroll
    for (int m = 8; m >= 1; m >>= 1) {
        #pragma unroll
        for (int r = 0; r < 4; ++r) ss[r] += __shfl_xor(ss[r], m, 64);
    }
    if (l15 == 0) {
        #pragma unroll
        for (int r = 0; r < 4; ++r) sm.ssq[nh][mh*16 + lq*4 + r] = ss[r];
    }
    __syncthreads();

    float sp[4];
    #pragma unroll
    for (int r = 0; r < 4; ++r) {
        int e = mh*16 + lq*4 + r;
        float rn = rsqrtf((sm.ssq[0][e] + sm.ssq[1][e]) * (1.0f/HID) + 1e-5f);
        sp[r] = siluf(acc0[r] * rn * g2v[0]) * w3v[0]
              + siluf(acc1[r] * rn * g2v[1]) * w3v[1]
              + siluf(acc2[r] * rn * g2v[2]) * w3v[2]
              + siluf(acc3[r] * rn * g2v[3]) * w3v[3];
    }
    #pragma unroll
    for (int m = 8; m >= 1; m >>= 1) {
        #pragma unroll
        for (int r = 0; r < 4; ++r) sp[r] += __shfl_xor(sp[r], m, 64);
    }
    if (l15 == 0) {
        #pragma unroll
        for (int r = 0; r < 4; ++r) sm.sedge[nh][mh*16 + lq*4 + r] = sp[r];
    }
    __syncthreads();

    // ---- final: edge scalar -> message accumulate (geometry wave owns cd) ----
    float a3x = 0.f, a3y = 0.f, a3z = 0.f;
    #pragma unroll
    for (int e = 0; e < 8; ++e) {
        int ge = eb + e;
        float s = sm.sedge[0][ge] + sm.sedge[1][ge] + b3s;
        a3x += cdx[e]*s; a3y += cdy[e]*s; a3z += cdz[e]*s;
    }
    if (lane == 0) { sm.wtr[wid][0] = a3x; sm.wtr[wid][1] = a3y; sm.wtr[wid][2] = a3z; }
    __syncthreads();
    if (tid < 3) {
        float v = pos[3*i + tid] +
                  (sm.wtr[0][tid] + sm.wtr[1][tid] + sm.wtr[2][tid] + sm.wtr[3][tid]) * (1.0f/KK);
        out[3*i + tid] = v;
    }
}

extern "C" void kernel_launch(void* const* d_in, const int* in_sizes, int n_in,
                              void* d_out, int out_size, void* d_ws, size_t ws_size,
                              hipStream_t stream) {
    (void)in_sizes; (void)n_in; (void)out_size;
    const float* pos = (const float*)d_in[0];
    const float* t   = (const float*)d_in[1];
    const float* W1  = (const float*)d_in[2];
    const float* b1  = (const float*)d_in[3];
    const float* g1  = (const float*)d_in[4];
    const float* W2  = (const float*)d_in[5];
    const float* b2  = (const float*)d_in[6];
    const float* g2  = (const float*)d_in[7];
    const float* W3  = (const float*)d_in[8];
    const float* b3  = (const float*)d_in[9];
    float* out = (float*)d_out;

    if (d_ws != nullptr && ws_size >= 32768) {
        prepack_w2<<<8, BLK, 0, stream>>>(W2, (uint4*)d_ws);
        egnn_main<true><<<NN, BLK, 0, stream>>>(
            pos, t, W1, b1, g1, W2, b2, g2, W3, b3, (const uint4*)d_ws, out);
    } else {
        egnn_main<false><<<NN, BLK, 0, stream>>>(
            pos, t, W1, b1, g1, W2, b2, g2, W3, b3, nullptr, out);
    }
}

// Round 10
// 134.163 us; speedup vs baseline: 1.5695x; 1.0191x over previous
//
#include <hip/hip_runtime.h>
#include <stdint.h>

#define NN   4096
#define KK   32
#define HID  128
#define BLK  256
#define NPB  2
#define GRID (NN / NPB)
#define CAP  128

typedef unsigned short bf16_t;
typedef __attribute__((ext_vector_type(8))) short bf16x8;
typedef __attribute__((ext_vector_type(4))) float f32x4;

__device__ __forceinline__ bf16_t f2bf(float f) {
    uint32_t u = __float_as_uint(f);
    u = u + 0x7fffu + ((u >> 16) & 1u);   // round-to-nearest-even
    return (bf16_t)(u >> 16);
}
__device__ __forceinline__ float siluf(float x) {
    return x / (1.0f + __expf(-x));
}

// ---- prepack: W2 fp32 -> bf16 in MFMA B-fragment order ----
// chunk c: frag f=c>>6 (f = NT*4+kk, NT=global n-tile 0..7), lane=c&63.
// contents: W2[row = NT*16+(lane&15)][k = kk*32+(lane>>4)*8 .. +8]
__global__ __launch_bounds__(BLK) void prepack_w2(
    const float* __restrict__ W2, uint4* __restrict__ w2b)
{
    int c  = blockIdx.x * BLK + threadIdx.x;
    int f  = c >> 6, ln = c & 63;
    int NT = f >> 2, kk = f & 3;
    int row = NT*16 + (ln & 15);
    int k0  = kk*32 + (ln >> 4) * 8;
    const float* s = W2 + row * HID + k0;
    float4 lo = *(const float4*)s;
    float4 hi = *(const float4*)(s + 4);
    uint4 pk;
    pk.x = (uint32_t)f2bf(lo.x) | ((uint32_t)f2bf(lo.y) << 16);
    pk.y = (uint32_t)f2bf(lo.z) | ((uint32_t)f2bf(lo.w) << 16);
    pk.z = (uint32_t)f2bf(hi.x) | ((uint32_t)f2bf(hi.y) << 16);
    pk.w = (uint32_t)f2bf(hi.z) | ((uint32_t)f2bf(hi.w) << 16);
    w2b[c] = pk;
}

template<bool WS>
struct __align__(16) Sm {
    union __align__(16) {                 // phase-disjoint reuse
        uint32_t hist[NPB][1024];         // 8 KB  (dist phase)
        ushort h1[64 * HID];              // 16 KB (MLP A-operand, swizzled)
    } u;
    uint32_t w2l[WS ? 4 : HID * 64];      // W2 LDS staging only in fallback
    unsigned long long cand[NPB][CAP];    // 2 KB
    float rads[64];
    float cdx[64], cdy[64], cdz[64];
    float sedge[64];
    int recvs[NPB][KK];
    int waveTot[NPB][4];
    unsigned long long redk[4];
    int pivotB[NPB];
    int cnt[NPB];
    int chosen;
};

template<bool WS>
__global__ __launch_bounds__(BLK) void egnn_main(
    const float* __restrict__ pos, const float* __restrict__ tptr,
    const float* __restrict__ W1,  const float* __restrict__ b1,
    const float* __restrict__ g1,  const float* __restrict__ W2,
    const float* __restrict__ b2,  const float* __restrict__ g2,
    const float* __restrict__ W3,  const float* __restrict__ b3,
    const uint4* __restrict__ w2b, float* __restrict__ out)
{
    __shared__ Sm<WS> sm;
    const int tid  = threadIdx.x;
    const int lane = tid & 63;
    const int wid  = tid >> 6;
    const int bid  = blockIdx.x;
    const int i0   = NPB * bid, i1 = i0 + 1;
    const int l15  = lane & 15, lq = lane >> 4;

    // ---- layer-1 per-lane constants: neurons 2*lane, 2*lane+1 ----
    const float ts   = tptr[0];
    const float4 w1v = ((const float4*)W1)[lane];     // (a0,b0,a1,b1)
    const float2 b1v = ((const float2*)b1)[lane];
    const float2 g1v = ((const float2*)g1)[lane];
    const float tc0  = ts * w1v.y + b1v.x;
    const float tc1  = ts * w1v.w + b1v.y;
    const float b3s  = b3[0];
    // closed-form RMS: sum_n (rad*a_n + c_n)^2 = rad^2*A2 + 2*rad*AC + C2
    float A2 = w1v.x*w1v.x + w1v.z*w1v.z;
    float AC = w1v.x*tc0   + w1v.z*tc1;
    float C2 = tc0*tc0     + tc1*tc1;
    #pragma unroll
    for (int m = 32; m >= 1; m >>= 1) {
        A2 += __shfl_xor(A2, m, 64);
        AC += __shfl_xor(AC, m, 64);
        C2 += __shfl_xor(C2, m, 64);
    }

    if constexpr (!WS) {
        for (int idx = tid; idx < HID * 16; idx += BLK) {
            int row = idx >> 4, c = idx & 15;
            const float* src = W2 + row * HID + c * 8;
            float4 lo = *(const float4*)src;
            float4 hi = *(const float4*)(src + 4);
            uint4 pk;
            pk.x = (uint32_t)f2bf(lo.x) | ((uint32_t)f2bf(lo.y) << 16);
            pk.y = (uint32_t)f2bf(lo.z) | ((uint32_t)f2bf(lo.w) << 16);
            pk.z = (uint32_t)f2bf(hi.x) | ((uint32_t)f2bf(hi.y) << 16);
            pk.w = (uint32_t)f2bf(hi.z) | ((uint32_t)f2bf(hi.w) << 16);
            *((uint4*)&sm.w2l[row * 64 + 4 * (c ^ (row & 15))]) = pk;
        }
    }
    // zero both histograms (2048 dwords = 512 uint4)
    ((uint4*)sm.u.hist)[tid]       = uint4{0u, 0u, 0u, 0u};
    ((uint4*)sm.u.hist)[tid + 256] = uint4{0u, 0u, 0u, 0u};
    if (tid == 0) { sm.cnt[0] = 0; sm.cnt[1] = 0; }
    __syncthreads();                                            // B1

    // node centers: pos[6*bid .. 6*bid+5] as 3x float2
    const float2 c01 = ((const float2*)pos)[3*bid    ];
    const float2 c23 = ((const float2*)pos)[3*bid + 1];
    const float2 c45 = ((const float2*)pos)[3*bid + 2];
    const float px0 = c01.x, py0 = c01.y, pz0 = c23.x;
    const float px1 = c23.y, py1 = c45.x, pz1 = c45.y;

    // ---- distances for BOTH nodes into registers + 2 LDS histograms ----
    // thread covers j = 1024*g + 4*tid + c; pos loads shared by both nodes
    float dreg0[4][4], dreg1[4][4];
    {
        const float4* p4 = (const float4*)pos;
        #pragma unroll
        for (int g = 0; g < 4; ++g) {
            float4 f0 = p4[768*g + 3*tid];
            float4 f1 = p4[768*g + 3*tid + 1];
            float4 f2 = p4[768*g + 3*tid + 2];
            float jx[4] = {f0.x, f0.w, f1.z, f2.y};
            float jy[4] = {f0.y, f1.x, f1.w, f2.z};
            float jz[4] = {f0.z, f1.y, f2.x, f2.w};
            #pragma unroll
            for (int c = 0; c < 4; ++c) {
                float dx0 = px0 - jx[c], dy0 = py0 - jy[c], dz0 = pz0 - jz[c];
                float d0 = __fadd_rn(__fadd_rn(__fmul_rn(dx0,dx0), __fmul_rn(dy0,dy0)),
                                     __fmul_rn(dz0,dz0));
                dreg0[g][c] = d0;
                atomicAdd((int*)&sm.u.hist[0][__float_as_uint(d0) >> 21], 1);
                float dx1 = px1 - jx[c], dy1 = py1 - jy[c], dz1 = pz1 - jz[c];
                float d1 = __fadd_rn(__fadd_rn(__fmul_rn(dx1,dx1), __fmul_rn(dy1,dy1)),
                                     __fmul_rn(dz1,dz1));
                dreg1[g][c] = d1;
                atomicAdd((int*)&sm.u.hist[1][__float_as_uint(d1) >> 21], 1);
            }
        }
    }
    // self-distances are exactly +0.0 (bucket 0): patch regs, deduct hist
    if (((i0 & 1023) >> 2) == tid) dreg0[i0 >> 10][i0 & 3] = __uint_as_float(0x7f800000u);
    if (((i1 & 1023) >> 2) == tid) dreg1[i1 >> 10][i1 & 3] = __uint_as_float(0x7f800000u);
    if (tid == 0) {
        atomicAdd((int*)&sm.u.hist[0][0], -1);
        atomicAdd((int*)&sm.u.hist[1][0], -1);
    }
    __syncthreads();                                            // B2

    // ---- fused pivot-bucket scan for both nodes ----
    {
        const int b0 = tid * 4;
        int a0 = (int)sm.u.hist[0][b0],   a1 = (int)sm.u.hist[0][b0+1];
        int a2 = (int)sm.u.hist[0][b0+2], a3 = (int)sm.u.hist[0][b0+3];
        int e0 = (int)sm.u.hist[1][b0],   e1 = (int)sm.u.hist[1][b0+1];
        int e2 = (int)sm.u.hist[1][b0+2], e3 = (int)sm.u.hist[1][b0+3];
        int s0 = a0+a1+a2+a3, s1 = e0+e1+e2+e3;
        int in0 = s0, in1 = s1;
        #pragma unroll
        for (int off = 1; off < 64; off <<= 1) {
            int v0 = __shfl_up(in0, off, 64);
            int v1 = __shfl_up(in1, off, 64);
            if (lane >= off) { in0 += v0; in1 += v1; }
        }
        if (lane == 63) { sm.waveTot[0][wid] = in0; sm.waveTot[1][wid] = in1; }
        __syncthreads();                                        // B3
        int base0 = 0, base1 = 0;
        for (int w = 0; w < wid; ++w) { base0 += sm.waveTot[0][w]; base1 += sm.waveTot[1][w]; }
        int E0 = base0 + in0 - s0;
        if (E0 < KK && E0 + s0 >= KK) {
            int cum = E0, B = b0 + 3;
            if (cum + a0 >= KK) B = b0;
            else { cum += a0;
                if (cum + a1 >= KK) B = b0 + 1;
                else { cum += a1; if (cum + a2 >= KK) B = b0 + 2; }
            }
            sm.pivotB[0] = B;
        }
        int E1 = base1 + in1 - s1;
        if (E1 < KK && E1 + s1 >= KK) {
            int cum = E1, B = b0 + 3;
            if (cum + e0 >= KK) B = b0;
            else { cum += e0;
                if (cum + e1 >= KK) B = b0 + 1;
                else { cum += e1; if (cum + e2 >= KK) B = b0 + 2; }
            }
            sm.pivotB[1] = B;
        }
    }
    __syncthreads();                                            // B4

    // ---- compaction (both nodes) ----
    {
        const int B0 = sm.pivotB[0], B1v = sm.pivotB[1];
        #pragma unroll
        for (int g = 0; g < 4; ++g) {
            #pragma unroll
            for (int c = 0; c < 4; ++c) {
                uint32_t ub0 = __float_as_uint(dreg0[g][c]);   // self=inf -> bucket>B
                if ((int)(ub0 >> 21) <= B0) {
                    int slot = atomicAdd(&sm.cnt[0], 1);
                    if (slot < CAP)
                        sm.cand[0][slot] = (((unsigned long long)ub0) << 12)
                                         | (unsigned)(1024*g + 4*tid + c);
                }
                uint32_t ub1 = __float_as_uint(dreg1[g][c]);
                if ((int)(ub1 >> 21) <= B1v) {
                    int slot = atomicAdd(&sm.cnt[1], 1);
                    if (slot < CAP)
                        sm.cand[1][slot] = (((unsigned long long)ub1) << 12)
                                         | (unsigned)(1024*g + 4*tid + c);
                }
            }
        }
    }
    __syncthreads();                                            // B5

    const int c0 = sm.cnt[0], c1v = sm.cnt[1];
    if (c0 <= CAP && c1v <= CAP) {
        // threads 0..127 rank node0 cands; 128..255 rank node1
        int nn = tid >> 7, tt = tid & 127;
        int cN = nn ? c1v : c0;
        if (tt < cN) {
            unsigned long long km = sm.cand[nn][tt];
            int rank = 0;
            for (int q = 0; q < cN; ++q)
                rank += (sm.cand[nn][q] < km) ? 1 : 0;
            if (rank < KK) sm.recvs[nn][rank] = (int)(km & 0xFFFull);
        }
    } else {
        // cold fallback (tie overflow): exact 32-pass argmin, node 0 then node 1
        for (int it = 0; it < KK; ++it) {
            unsigned long long best = ~0ull;
            #pragma unroll
            for (int g = 0; g < 4; ++g)
                #pragma unroll
                for (int c = 0; c < 4; ++c) {
                    unsigned long long key =
                        (((unsigned long long)__float_as_uint(dreg0[g][c])) << 12)
                        | (unsigned)(1024*g + 4*tid + c);
                    best = best < key ? best : key;
                }
            #pragma unroll
            for (int m = 32; m >= 1; m >>= 1) {
                unsigned long long o = __shfl_xor(best, m, 64);
                best = best < o ? best : o;
            }
            if (lane == 0) sm.redk[wid] = best;
            __syncthreads();
            if (tid == 0) {
                unsigned long long b01 = sm.redk[0] < sm.redk[1] ? sm.redk[0] : sm.redk[1];
                unsigned long long b23 = sm.redk[2] < sm.redk[3] ? sm.redk[2] : sm.redk[3];
                unsigned long long b   = b01 < b23 ? b01 : b23;
                int j = (int)(b & 0xfffull);
                sm.recvs[0][it] = j; sm.chosen = j;
            }
            __syncthreads();
            int j = sm.chosen;
            if (((j & 1023) >> 2) == tid) dreg0[j >> 10][j & 3] = __uint_as_float(0x7f800000u);
        }
        for (int it = 0; it < KK; ++it) {
            unsigned long long best = ~0ull;
            #pragma unroll
            for (int g = 0; g < 4; ++g)
                #pragma unroll
                for (int c = 0; c < 4; ++c) {
                    unsigned long long key =
                        (((unsigned long long)__float_as_uint(dreg1[g][c])) << 12)
                        | (unsigned)(1024*g + 4*tid + c);
                    best = best < key ? best : key;
                }
            #pragma unroll
            for (int m = 32; m >= 1; m >>= 1) {
                unsigned long long o = __shfl_xor(best, m, 64);
                best = best < o ? best : o;
            }
            if (lane == 0) sm.redk[wid] = best;
            __syncthreads();
            if (tid == 0) {
                unsigned long long b01 = sm.redk[0] < sm.redk[1] ? sm.redk[0] : sm.redk[1];
                unsigned long long b23 = sm.redk[2] < sm.redk[3] ? sm.redk[2] : sm.redk[3];
                unsigned long long b   = b01 < b23 ? b01 : b23;
                int j = (int)(b & 0xfffull);
                sm.recvs[1][it] = j; sm.chosen = j;
            }
            __syncthreads();
            int j = sm.chosen;
            if (((j & 1023) >> 2) == tid) dreg1[j >> 10][j & 3] = __uint_as_float(0x7f800000u);
        }
    }
    __syncthreads();                                            // B6

    // ---- edge gather: wave 0, lane e (0..63): node e>>5, neighbor recvs[...] ----
    if (wid == 0) {
        int ne = lane >> 5;
        int r  = sm.recvs[ne][lane & 31];
        float cx = (ne ? px1 : px0) - pos[3*r];
        float cy = (ne ? py1 : py0) - pos[3*r+1];
        float cz = (ne ? pz1 : pz0) - pos[3*r+2];
        sm.cdx[lane] = cx; sm.cdy[lane] = cy; sm.cdz[lane] = cz;
        sm.rads[lane] = __fadd_rn(__fadd_rn(__fmul_rn(cx,cx), __fmul_rn(cy,cy)),
                                  __fmul_rn(cz,cz));
    }
    __syncthreads();                                            // B7

    // ---- layer 1: wave w owns edges [16w, 16w+16); closed-form RMS ----
    {
        uint32_t* h1d = (uint32_t*)sm.u.h1;
        const int ch = lane >> 2, dw = lane & 3;
        #pragma unroll
        for (int e = 0; e < 16; ++e) {
            int ge = 16*wid + e;
            float rad = sm.rads[ge];                 // LDS broadcast
            float sqv = rad*rad*A2 + 2.0f*rad*AC + C2;
            float rn  = rsqrtf(sqv * (1.0f/HID) + 1e-5f);
            float p0  = rad * w1v.x + tc0;
            float p1  = rad * w1v.z + tc1;
            float a = siluf(p0 * rn * g1v.x);
            float b = siluf(p1 * rn * g1v.y);
            uint32_t pk = (__float_as_uint(a) >> 16) | (__float_as_uint(b) & 0xffff0000u);
            h1d[ge*64 + ((ch ^ (ge & 15)))*4 + dw] = pk;
        }
    }
    __syncthreads();                                            // B8

    // ---- layer 2 via MFMA: wave w = m-tile w (16 edges), ALL 8 n-tiles ----
    f32x4 acc[8];
    #pragma unroll
    for (int nt = 0; nt < 8; ++nt) acc[nt] = f32x4{0.f, 0.f, 0.f, 0.f};
    {
        const bf16x8* h1v = (const bf16x8*)sm.u.h1;   // [64][16 chunks]
        const int m = 16*wid + l15;
        if constexpr (WS) {
            const bf16x8* bv = (const bf16x8*)w2b;
            #pragma unroll
            for (int kk = 0; kk < 4; ++kk) {
                bf16x8 af = h1v[m*16 + ((kk*4 + lq) ^ l15)];
                #pragma unroll
                for (int nt = 0; nt < 8; ++nt)
                    acc[nt] = __builtin_amdgcn_mfma_f32_16x16x32_bf16(
                                  af, bv[(nt*4 + kk)*64 + lane], acc[nt], 0, 0, 0);
            }
        } else {
            const bf16x8* w2v = (const bf16x8*)sm.w2l;    // [128][16 chunks]
            #pragma unroll
            for (int kk = 0; kk < 4; ++kk) {
                const int q = (kk*4 + lq) ^ l15;
                bf16x8 af = h1v[m*16 + q];
                #pragma unroll
                for (int nt = 0; nt < 8; ++nt)
                    acc[nt] = __builtin_amdgcn_mfma_f32_16x16x32_bf16(
                                  af, w2v[(nt*16 + l15)*16 + q], acc[nt], 0, 0, 0);
            }
        }
    }

    // ---- epilogue (fully wave-local): n = nt*16 + l15 ----
    float g2v[8], w3v[8], b2v[8];
    #pragma unroll
    for (int nt = 0; nt < 8; ++nt) {
        int n = nt*16 + l15;
        g2v[nt] = g2[n]; w3v[nt] = W3[n]; b2v[nt] = b2[n];
    }
    float ss[4];
    #pragma unroll
    for (int r = 0; r < 4; ++r) {
        float t = 0.f;
        #pragma unroll
        for (int nt = 0; nt < 8; ++nt) {
            float zz = acc[nt][r] + b2v[nt];
            acc[nt][r] = zz;
            t += zz*zz;
        }
        ss[r] = t;
    }
    #pragma unroll
    for (int m = 8; m >= 1; m >>= 1) {
        #pragma unroll
        for (int r = 0; r < 4; ++r) ss[r] += __shfl_xor(ss[r], m, 64);
    }
    float sp[4];
    #pragma unroll
    for (int r = 0; r < 4; ++r) {
        float rn = rsqrtf(ss[r] * (1.0f/HID) + 1e-5f);
        float t = 0.f;
        #pragma unroll
        for (int nt = 0; nt < 8; ++nt)
            t += siluf(acc[nt][r] * rn * g2v[nt]) * w3v[nt];
        sp[r] = t;
    }
    #pragma unroll
    for (int m = 8; m >= 1; m >>= 1) {
        #pragma unroll
        for (int r = 0; r < 4; ++r) sp[r] += __shfl_xor(sp[r], m, 64);
    }
    if (l15 == 0) {
        #pragma unroll
        for (int r = 0; r < 4; ++r)
            sm.sedge[16*wid + lq*4 + r] = sp[r] + b3s;   // edge scalar (b3 folded)
    }
    __syncthreads();                                            // B9

    // ---- final: wave w (w<2) sums node w's 32 edge messages lane-parallel ----
    if (wid < NPB) {
        bool act = lane < KK;
        int e = KK*wid + (lane & 31);
        float s  = act ? sm.sedge[e] : 0.f;
        float mx = act ? sm.cdx[e] * s : 0.f;
        float my = act ? sm.cdy[e] * s : 0.f;
        float mz = act ? sm.cdz[e] * s : 0.f;
        #pragma unroll
        for (int m = 16; m >= 1; m >>= 1) {
            mx += __shfl_xor(mx, m, 64);
            my += __shfl_xor(my, m, 64);
            mz += __shfl_xor(mz, m, 64);
        }
        if (lane == 0) {
            int node = i0 + wid;
            out[3*node    ] = (wid ? px1 : px0) + mx * (1.0f/KK);
            out[3*node + 1] = (wid ? py1 : py0) + my * (1.0f/KK);
            out[3*node + 2] = (wid ? pz1 : pz0) + mz * (1.0f/KK);
        }
    }
}

extern "C" void kernel_launch(void* const* d_in, const int* in_sizes, int n_in,
                              void* d_out, int out_size, void* d_ws, size_t ws_size,
                              hipStream_t stream) {
    (void)in_sizes; (void)n_in; (void)out_size;
    const float* pos = (const float*)d_in[0];
    const float* t   = (const float*)d_in[1];
    const float* W1  = (const float*)d_in[2];
    const float* b1  = (const float*)d_in[3];
    const float* g1  = (const float*)d_in[4];
    const float* W2  = (const float*)d_in[5];
    const float* b2  = (const float*)d_in[6];
    const float* g2  = (const float*)d_in[7];
    const float* W3  = (const float*)d_in[8];
    const float* b3  = (const float*)d_in[9];
    float* out = (float*)d_out;

    if (d_ws != nullptr && ws_size >= 32768) {
        prepack_w2<<<8, BLK, 0, stream>>>(W2, (uint4*)d_ws);
        egnn_main<true><<<GRID, BLK, 0, stream>>>(
            pos, t, W1, b1, g1, W2, b2, g2, W3, b3, (const uint4*)d_ws, out);
    } else {
        egnn_main<false><<<GRID, BLK, 0, stream>>>(
            pos, t, W1, b1, g1, W2, b2, g2, W3, b3, nullptr, out);
    }
}

// Round 11
// 131.722 us; speedup vs baseline: 1.5986x; 1.0185x over previous
//
#include <hip/hip_runtime.h>
#include <stdint.h>

#define NN   4096
#define KK   32
#define HID  128
#define BLK  256
#define NPB  2
#define GRID (NN / NPB)
#define CAP  128

typedef unsigned short bf16_t;
typedef __attribute__((ext_vector_type(8))) short bf16x8;
typedef __attribute__((ext_vector_type(4))) float f32x4;

__device__ __forceinline__ bf16_t f2bf(float f) {
    uint32_t u = __float_as_uint(f);
    u = u + 0x7fffu + ((u >> 16) & 1u);   // round-to-nearest-even
    return (bf16_t)(u >> 16);
}
__device__ __forceinline__ float siluf(float x) {
    return x / (1.0f + __expf(-x));
}

// ---- prepack: W2 fp32 -> bf16 in MFMA B-fragment order ----
// chunk c: frag f=c>>6 (f = NT*4+kk, NT=n-tile 0..7), lane=c&63.
// contents: W2[row = NT*16+(lane&15)][k = kk*32+(lane>>4)*8 .. +8]
__global__ __launch_bounds__(BLK) void prepack_w2(
    const float* __restrict__ W2, uint4* __restrict__ w2b)
{
    int c  = blockIdx.x * BLK + threadIdx.x;
    int f  = c >> 6, ln = c & 63;
    int NT = f >> 2, kk = f & 3;
    int row = NT*16 + (ln & 15);
    int k0  = kk*32 + (ln >> 4) * 8;
    const float* s = W2 + row * HID + k0;
    float4 lo = *(const float4*)s;
    float4 hi = *(const float4*)(s + 4);
    uint4 pk;
    pk.x = (uint32_t)f2bf(lo.x) | ((uint32_t)f2bf(lo.y) << 16);
    pk.y = (uint32_t)f2bf(lo.z) | ((uint32_t)f2bf(lo.w) << 16);
    pk.z = (uint32_t)f2bf(hi.x) | ((uint32_t)f2bf(hi.y) << 16);
    pk.w = (uint32_t)f2bf(hi.z) | ((uint32_t)f2bf(hi.w) << 16);
    w2b[c] = pk;
}

template<bool WS>
struct __align__(16) Sm {
    union __align__(16) {                 // phase-disjoint reuse (16 KB both ways)
        uint32_t hist[NPB][2][1024];      // per-node, 2 sub-hists (lane parity)
        ushort h1[64 * HID];              // MLP A-operand, bf16, swizzled chunks
    } u;
    uint32_t w2l[WS ? 4 : HID * 64];      // W2 LDS staging only in fallback
    unsigned long long cand[NPB][CAP];    // 2 KB
    float sedge[64];
    int recvs[NPB][KK];
    int waveTot[NPB][4];
    unsigned long long redk[4];
    int pivotB[NPB];
    int cnt[NPB];
    int chosen;
};

template<bool WS>
__global__ __launch_bounds__(BLK) void egnn_main(
    const float* __restrict__ pos, const float* __restrict__ tptr,
    const float* __restrict__ W1,  const float* __restrict__ b1,
    const float* __restrict__ g1,  const float* __restrict__ W2,
    const float* __restrict__ b2,  const float* __restrict__ g2,
    const float* __restrict__ W3,  const float* __restrict__ b3,
    const uint4* __restrict__ w2b, float* __restrict__ out)
{
    __shared__ Sm<WS> sm;
    const int tid  = threadIdx.x;
    const int lane = tid & 63;
    const int wid  = tid >> 6;
    const int bid  = blockIdx.x;
    const int i0   = NPB * bid, i1 = i0 + 1;
    const int l15  = lane & 15, lq = lane >> 4;

    const float ts  = tptr[0];
    const float b3s = b3[0];

    // closed-form RMS coefficients (node-independent): computed once, 3 regs kept.
    // sum_n (rad*a_n + c_n)^2 = rad^2*A2 + 2*rad*AC + C2
    float A2, AC, C2;
    {
        const float4 w1v = ((const float4*)W1)[lane];     // rows 2l,2l+1
        const float2 b1v = ((const float2*)b1)[lane];
        float t0 = ts * w1v.y + b1v.x;
        float t1 = ts * w1v.w + b1v.y;
        A2 = w1v.x*w1v.x + w1v.z*w1v.z;
        AC = w1v.x*t0    + w1v.z*t1;
        C2 = t0*t0       + t1*t1;
        #pragma unroll
        for (int m = 32; m >= 1; m >>= 1) {
            A2 += __shfl_xor(A2, m, 64);
            AC += __shfl_xor(AC, m, 64);
            C2 += __shfl_xor(C2, m, 64);
        }
    }

    if constexpr (!WS) {
        for (int idx = tid; idx < HID * 16; idx += BLK) {
            int row = idx >> 4, c = idx & 15;
            const float* src = W2 + row * HID + c * 8;
            float4 lo = *(const float4*)src;
            float4 hi = *(const float4*)(src + 4);
            uint4 pk;
            pk.x = (uint32_t)f2bf(lo.x) | ((uint32_t)f2bf(lo.y) << 16);
            pk.y = (uint32_t)f2bf(lo.z) | ((uint32_t)f2bf(lo.w) << 16);
            pk.z = (uint32_t)f2bf(hi.x) | ((uint32_t)f2bf(hi.y) << 16);
            pk.w = (uint32_t)f2bf(hi.z) | ((uint32_t)f2bf(hi.w) << 16);
            *((uint4*)&sm.w2l[row * 64 + 4 * (c ^ (row & 15))]) = pk;
        }
    }
    // zero histograms: 4096 dwords = 1024 uint4, 4 per thread
    {
        uint4 z = uint4{0u, 0u, 0u, 0u};
        uint4* hz = (uint4*)sm.u.hist;
        hz[tid] = z; hz[tid+256] = z; hz[tid+512] = z; hz[tid+768] = z;
    }
    if (tid == 0) { sm.cnt[0] = 0; sm.cnt[1] = 0; }
    __syncthreads();                                            // B1

    // node centers: pos[6*bid .. +5] as 3x float2
    const float2 c01 = ((const float2*)pos)[3*bid    ];
    const float2 c23 = ((const float2*)pos)[3*bid + 1];
    const float2 c45 = ((const float2*)pos)[3*bid + 2];
    const float px0 = c01.x, py0 = c01.y, pz0 = c23.x;
    const float px1 = c23.y, py1 = c45.x, pz1 = c45.y;

    // ---- distances for BOTH nodes into registers + sub-split LDS histograms ----
    const int par = tid & 1;
    float dreg0[4][4], dreg1[4][4];
    {
        const float4* p4 = (const float4*)pos;
        #pragma unroll
        for (int g = 0; g < 4; ++g) {
            float4 f0 = p4[768*g + 3*tid];
            float4 f1 = p4[768*g + 3*tid + 1];
            float4 f2 = p4[768*g + 3*tid + 2];
            float jx[4] = {f0.x, f0.w, f1.z, f2.y};
            float jy[4] = {f0.y, f1.x, f1.w, f2.z};
            float jz[4] = {f0.z, f1.y, f2.x, f2.w};
            #pragma unroll
            for (int c = 0; c < 4; ++c) {
                float dx0 = px0 - jx[c], dy0 = py0 - jy[c], dz0 = pz0 - jz[c];
                float d0 = __fadd_rn(__fadd_rn(__fmul_rn(dx0,dx0), __fmul_rn(dy0,dy0)),
                                     __fmul_rn(dz0,dz0));
                dreg0[g][c] = d0;
                atomicAdd((int*)&sm.u.hist[0][par][__float_as_uint(d0) >> 21], 1);
                float dx1 = px1 - jx[c], dy1 = py1 - jy[c], dz1 = pz1 - jz[c];
                float d1 = __fadd_rn(__fadd_rn(__fmul_rn(dx1,dx1), __fmul_rn(dy1,dy1)),
                                     __fmul_rn(dz1,dz1));
                dreg1[g][c] = d1;
                atomicAdd((int*)&sm.u.hist[1][par][__float_as_uint(d1) >> 21], 1);
            }
        }
    }
    // self-distances are exactly +0.0 (bucket 0): patch regs, deduct correct sub-hist
    if (((i0 & 1023) >> 2) == tid) dreg0[i0 >> 10][i0 & 3] = __uint_as_float(0x7f800000u);
    if (((i1 & 1023) >> 2) == tid) dreg1[i1 >> 10][i1 & 3] = __uint_as_float(0x7f800000u);
    if (tid == 0) {
        atomicAdd((int*)&sm.u.hist[0][((i0 & 1023) >> 2) & 1][0], -1);
        atomicAdd((int*)&sm.u.hist[1][((i1 & 1023) >> 2) & 1][0], -1);
    }
    __syncthreads();                                            // B2

    // ---- fused pivot-bucket scan for both nodes (sub-hists summed) ----
    {
        const int b0 = tid * 4;
        uint4 qa0 = *(const uint4*)&sm.u.hist[0][0][b0];
        uint4 qa1 = *(const uint4*)&sm.u.hist[0][1][b0];
        uint4 qb0 = *(const uint4*)&sm.u.hist[1][0][b0];
        uint4 qb1 = *(const uint4*)&sm.u.hist[1][1][b0];
        int a0 = (int)(qa0.x+qa1.x), a1 = (int)(qa0.y+qa1.y);
        int a2 = (int)(qa0.z+qa1.z), a3 = (int)(qa0.w+qa1.w);
        int e0 = (int)(qb0.x+qb1.x), e1 = (int)(qb0.y+qb1.y);
        int e2 = (int)(qb0.z+qb1.z), e3 = (int)(qb0.w+qb1.w);
        int s0 = a0+a1+a2+a3, s1 = e0+e1+e2+e3;
        int in0 = s0, in1 = s1;
        #pragma unroll
        for (int off = 1; off < 64; off <<= 1) {
            int v0 = __shfl_up(in0, off, 64);
            int v1 = __shfl_up(in1, off, 64);
            if (lane >= off) { in0 += v0; in1 += v1; }
        }
        if (lane == 63) { sm.waveTot[0][wid] = in0; sm.waveTot[1][wid] = in1; }
        __syncthreads();                                        // B3
        int base0 = 0, base1 = 0;
        for (int w = 0; w < wid; ++w) { base0 += sm.waveTot[0][w]; base1 += sm.waveTot[1][w]; }
        int E0 = base0 + in0 - s0;
        if (E0 < KK && E0 + s0 >= KK) {
            int cum = E0, B = b0 + 3;
            if (cum + a0 >= KK) B = b0;
            else { cum += a0;
                if (cum + a1 >= KK) B = b0 + 1;
                else { cum += a1; if (cum + a2 >= KK) B = b0 + 2; }
            }
            sm.pivotB[0] = B;
        }
        int E1 = base1 + in1 - s1;
        if (E1 < KK && E1 + s1 >= KK) {
            int cum = E1, B = b0 + 3;
            if (cum + e0 >= KK) B = b0;
            else { cum += e0;
                if (cum + e1 >= KK) B = b0 + 1;
                else { cum += e1; if (cum + e2 >= KK) B = b0 + 2; }
            }
            sm.pivotB[1] = B;
        }
    }
    __syncthreads();                                            // B4

    // ---- compaction (both nodes) ----
    {
        const int B0 = sm.pivotB[0], B1v = sm.pivotB[1];
        #pragma unroll
        for (int g = 0; g < 4; ++g) {
            #pragma unroll
            for (int c = 0; c < 4; ++c) {
                uint32_t ub0 = __float_as_uint(dreg0[g][c]);   // self=inf -> bucket>B
                if ((int)(ub0 >> 21) <= B0) {
                    int slot = atomicAdd(&sm.cnt[0], 1);
                    if (slot < CAP)
                        sm.cand[0][slot] = (((unsigned long long)ub0) << 12)
                                         | (unsigned)(1024*g + 4*tid + c);
                }
                uint32_t ub1 = __float_as_uint(dreg1[g][c]);
                if ((int)(ub1 >> 21) <= B1v) {
                    int slot = atomicAdd(&sm.cnt[1], 1);
                    if (slot < CAP)
                        sm.cand[1][slot] = (((unsigned long long)ub1) << 12)
                                         | (unsigned)(1024*g + 4*tid + c);
                }
            }
        }
    }
    __syncthreads();                                            // B5

    const int c0 = sm.cnt[0], c1v = sm.cnt[1];
    if (c0 <= CAP && c1v <= CAP) {
        // threads 0..127 rank node0 cands; 128..255 rank node1
        int nn = tid >> 7, tt = tid & 127;
        int cN = nn ? c1v : c0;
        if (tt < cN) {
            unsigned long long km = sm.cand[nn][tt];
            int rank = 0;
            for (int q = 0; q < cN; ++q)
                rank += (sm.cand[nn][q] < km) ? 1 : 0;
            if (rank < KK) sm.recvs[nn][rank] = (int)(km & 0xFFFull);
        }
    } else {
        // cold fallback (tie overflow): exact 32-pass argmin, node 0 then node 1
        for (int it = 0; it < KK; ++it) {
            unsigned long long best = ~0ull;
            #pragma unroll
            for (int g = 0; g < 4; ++g)
                #pragma unroll
                for (int c = 0; c < 4; ++c) {
                    unsigned long long key =
                        (((unsigned long long)__float_as_uint(dreg0[g][c])) << 12)
                        | (unsigned)(1024*g + 4*tid + c);
                    best = best < key ? best : key;
                }
            #pragma unroll
            for (int m = 32; m >= 1; m >>= 1) {
                unsigned long long o = __shfl_xor(best, m, 64);
                best = best < o ? best : o;
            }
            if (lane == 0) sm.redk[wid] = best;
            __syncthreads();
            if (tid == 0) {
                unsigned long long b01 = sm.redk[0] < sm.redk[1] ? sm.redk[0] : sm.redk[1];
                unsigned long long b23 = sm.redk[2] < sm.redk[3] ? sm.redk[2] : sm.redk[3];
                unsigned long long b   = b01 < b23 ? b01 : b23;
                int j = (int)(b & 0xfffull);
                sm.recvs[0][it] = j; sm.chosen = j;
            }
            __syncthreads();
            int j = sm.chosen;
            if (((j & 1023) >> 2) == tid) dreg0[j >> 10][j & 3] = __uint_as_float(0x7f800000u);
        }
        for (int it = 0; it < KK; ++it) {
            unsigned long long best = ~0ull;
            #pragma unroll
            for (int g = 0; g < 4; ++g)
                #pragma unroll
                for (int c = 0; c < 4; ++c) {
                    unsigned long long key =
                        (((unsigned long long)__float_as_uint(dreg1[g][c])) << 12)
                        | (unsigned)(1024*g + 4*tid + c);
                    best = best < key ? best : key;
                }
            #pragma unroll
            for (int m = 32; m >= 1; m >>= 1) {
                unsigned long long o = __shfl_xor(best, m, 64);
                best = best < o ? best : o;
            }
            if (lane == 0) sm.redk[wid] = best;
            __syncthreads();
            if (tid == 0) {
                unsigned long long b01 = sm.redk[0] < sm.redk[1] ? sm.redk[0] : sm.redk[1];
                unsigned long long b23 = sm.redk[2] < sm.redk[3] ? sm.redk[2] : sm.redk[3];
                unsigned long long b   = b01 < b23 ? b01 : b23;
                int j = (int)(b & 0xfffull);
                sm.recvs[1][it] = j; sm.chosen = j;
            }
            __syncthreads();
            int j = sm.chosen;
            if (((j & 1023) >> 2) == tid) dreg1[j >> 10][j & 3] = __uint_as_float(0x7f800000u);
        }
    }
    __syncthreads();                                            // B6

    // ---- layer 1 fused with edge gather; writes wave-local h1 rows as b128 ----
    // lane = ch*4 + epr: chunk ch (neurons 8ch..8ch+7), edge-in-group epr.
    // wave w owns edges/rows [16w, 16w+16); node = w>>1 (wave-uniform).
    {
        const int ch = lane >> 2, epr = lane & 3;
        // per-lane 8-neuron constants (short live range, loaded post-selection)
        float4 wA = ((const float4*)W1)[ch*4    ];
        float4 wB = ((const float4*)W1)[ch*4 + 1];
        float4 wC = ((const float4*)W1)[ch*4 + 2];
        float4 wD = ((const float4*)W1)[ch*4 + 3];
        float4 bA = ((const float4*)b1)[ch*2], bB = ((const float4*)b1)[ch*2 + 1];
        float4 gA = ((const float4*)g1)[ch*2], gB = ((const float4*)g1)[ch*2 + 1];
        float av[8] = {wA.x, wA.z, wB.x, wB.z, wC.x, wC.z, wD.x, wD.z};
        float cv[8] = {ts*wA.y + bA.x, ts*wA.w + bA.y, ts*wB.y + bA.z, ts*wB.w + bA.w,
                       ts*wC.y + bB.x, ts*wC.w + bB.y, ts*wD.y + bB.z, ts*wD.w + bB.w};
        float gv[8] = {gA.x, gA.y, gA.z, gA.w, gB.x, gB.y, gB.z, gB.w};

        const int nodeW = wid >> 1;
        const float pxw = nodeW ? px1 : px0;
        const float pyw = nodeW ? py1 : py0;
        const float pzw = nodeW ? pz1 : pz0;
        uint4* h1q = (uint4*)sm.u.h1;
        #pragma unroll
        for (int g = 0; g < 4; ++g) {
            int E = 16*wid + 4*g + epr;
            int r = sm.recvs[nodeW][E & 31];
            float dx = pxw - pos[3*r];
            float dy = pyw - pos[3*r+1];
            float dz = pzw - pos[3*r+2];
            float rad = __fadd_rn(__fadd_rn(__fmul_rn(dx,dx), __fmul_rn(dy,dy)),
                                  __fmul_rn(dz,dz));
            float sqv = rad*rad*A2 + 2.0f*rad*AC + C2;
            float rn  = rsqrtf(sqv * (1.0f/HID) + 1e-5f);
            uint32_t pk[4];
            #pragma unroll
            for (int p = 0; p < 4; ++p) {
                float va = siluf((rad*av[2*p]   + cv[2*p])   * rn * gv[2*p]);
                float vb = siluf((rad*av[2*p+1] + cv[2*p+1]) * rn * gv[2*p+1]);
                pk[p] = (__float_as_uint(va) >> 16) | (__float_as_uint(vb) & 0xffff0000u);
            }
            h1q[E*16 + (ch ^ (E & 15))] = uint4{pk[0], pk[1], pk[2], pk[3]};
        }
    }
    // no barrier: h1 rows [16w,16w+16) are written and read only by wave w
    // (compiler orders ds_write -> ds_read via lgkmcnt)

    // ---- layer 2 via MFMA: wave w = m-tile w (16 edges), ALL 8 n-tiles ----
    f32x4 acc[8];
    #pragma unroll
    for (int nt = 0; nt < 8; ++nt) acc[nt] = f32x4{0.f, 0.f, 0.f, 0.f};
    {
        const bf16x8* h1v = (const bf16x8*)sm.u.h1;   // [64][16 chunks]
        const int m = 16*wid + l15;
        if constexpr (WS) {
            const bf16x8* bv = (const bf16x8*)w2b;
            #pragma unroll
            for (int kk = 0; kk < 4; ++kk) {
                bf16x8 af = h1v[m*16 + ((kk*4 + lq) ^ l15)];
                #pragma unroll
                for (int nt = 0; nt < 8; ++nt)
                    acc[nt] = __builtin_amdgcn_mfma_f32_16x16x32_bf16(
                                  af, bv[(nt*4 + kk)*64 + lane], acc[nt], 0, 0, 0);
            }
        } else {
            const bf16x8* w2v = (const bf16x8*)sm.w2l;    // [128][16 chunks]
            #pragma unroll
            for (int kk = 0; kk < 4; ++kk) {
                const int q = (kk*4 + lq) ^ l15;
                bf16x8 af = h1v[m*16 + q];
                #pragma unroll
                for (int nt = 0; nt < 8; ++nt)
                    acc[nt] = __builtin_amdgcn_mfma_f32_16x16x32_bf16(
                                  af, w2v[(nt*16 + l15)*16 + q], acc[nt], 0, 0, 0);
            }
        }
    }

    // ---- epilogue (fully wave-local): n = nt*16 + l15 ----
    float g2v[8], w3v[8], b2v[8];
    #pragma unroll
    for (int nt = 0; nt < 8; ++nt) {
        int n = nt*16 + l15;
        g2v[nt] = g2[n]; w3v[nt] = W3[n]; b2v[nt] = b2[n];
    }
    float ss[4];
    #pragma unroll
    for (int r = 0; r < 4; ++r) {
        float t = 0.f;
        #pragma unroll
        for (int nt = 0; nt < 8; ++nt) {
            float zz = acc[nt][r] + b2v[nt];
            acc[nt][r] = zz;
            t += zz*zz;
        }
        ss[r] = t;
    }
    #pragma unroll
    for (int m = 8; m >= 1; m >>= 1) {
        #pragma unroll
        for (int r = 0; r < 4; ++r) ss[r] += __shfl_xor(ss[r], m, 64);
    }
    float sp[4];
    #pragma unroll
    for (int r = 0; r < 4; ++r) {
        float rn = rsqrtf(ss[r] * (1.0f/HID) + 1e-5f);
        float t = 0.f;
        #pragma unroll
        for (int nt = 0; nt < 8; ++nt)
            t += siluf(acc[nt][r] * rn * g2v[nt]) * w3v[nt];
        sp[r] = t;
    }
    #pragma unroll
    for (int m = 8; m >= 1; m >>= 1) {
        #pragma unroll
        for (int r = 0; r < 4; ++r) sp[r] += __shfl_xor(sp[r], m, 64);
    }
    if (l15 == 0) {
        #pragma unroll
        for (int r = 0; r < 4; ++r)
            sm.sedge[16*wid + lq*4 + r] = sp[r] + b3s;   // edge scalar (b3 folded)
    }
    __syncthreads();                                            // B7

    // ---- final: wave w (w<2) sums node w's 32 edge messages lane-parallel;
    //      cd re-gathered from L2-hot pos (cheaper than LDS staging) ----
    if (wid < NPB) {
        float mx = 0.f, my = 0.f, mz = 0.f;
        if (lane < KK) {
            int r = sm.recvs[wid][lane];
            float cx = (wid ? px1 : px0) - pos[3*r];
            float cy = (wid ? py1 : py0) - pos[3*r+1];
            float cz = (wid ? pz1 : pz0) - pos[3*r+2];
            float s  = sm.sedge[KK*wid + lane];
            mx = cx * s; my = cy * s; mz = cz * s;
        }
        #pragma unroll
        for (int m = 16; m >= 1; m >>= 1) {
            mx += __shfl_xor(mx, m, 64);
            my += __shfl_xor(my, m, 64);
            mz += __shfl_xor(mz, m, 64);
        }
        if (lane == 0) {
            int node = i0 + wid;
            out[3*node    ] = (wid ? px1 : px0) + mx * (1.0f/KK);
            out[3*node + 1] = (wid ? py1 : py0) + my * (1.0f/KK);
            out[3*node + 2] = (wid ? pz1 : pz0) + mz * (1.0f/KK);
        }
    }
}

extern "C" void kernel_launch(void* const* d_in, const int* in_sizes, int n_in,
                              void* d_out, int out_size, void* d_ws, size_t ws_size,
                              hipStream_t stream) {
    (void)in_sizes; (void)n_in; (void)out_size;
    const float* pos = (const float*)d_in[0];
    const float* t   = (const float*)d_in[1];
    const float* W1  = (const float*)d_in[2];
    const float* b1  = (const float*)d_in[3];
    const float* g1  = (const float*)d_in[4];
    const float* W2  = (const float*)d_in[5];
    const float* b2  = (const float*)d_in[6];
    const float* g2  = (const float*)d_in[7];
    const float* W3  = (const float*)d_in[8];
    const float* b3  = (const float*)d_in[9];
    float* out = (float*)d_out;

    if (d_ws != nullptr && ws_size >= 32768) {
        prepack_w2<<<8, BLK, 0, stream>>>(W2, (uint4*)d_ws);
        egnn_main<true><<<GRID, BLK, 0, stream>>>(
            pos, t, W1, b1, g1, W2, b2, g2, W3, b3, (const uint4*)d_ws, out);
    } else {
        egnn_main<false><<<GRID, BLK, 0, stream>>>(
            pos, t, W1, b1, g1, W2, b2, g2, W3, b3, nullptr, out);
    }
}